// Round 12
// baseline (444.223 us; speedup 1.0000x reference)
//
#include <hip/hip_runtime.h>
#include <cmath>

// B=64, L=512, H=64, 2H=128, OUT=5
static constexpr int kB = 64, kL = 512, kH = 64, kH2 = 128, kOut = 5;

typedef short bf16x8 __attribute__((ext_vector_type(8)));
typedef float f32x4  __attribute__((ext_vector_type(4)));

__device__ __forceinline__ unsigned short f2bf(float f) {
  unsigned u = __float_as_uint(f);
  unsigned r = (u + 0x7FFFu + ((u >> 16) & 1u)) >> 16;   // RNE
  return (unsigned short)r;
}

__device__ __forceinline__ void cvt8(const f32x4& v0, const f32x4& v1,
                                     bf16x8& hi, bf16x8& lo) {
  #pragma unroll
  for (int j = 0; j < 4; ++j) {
    unsigned short h0 = f2bf(v0[j]);
    unsigned short h1 = f2bf(v1[j]);
    hi[j]     = (short)h0;
    hi[j + 4] = (short)h1;
    lo[j]     = (short)f2bf(v0[j] - __uint_as_float(((unsigned)h0) << 16));
    lo[j + 4] = (short)f2bf(v1[j] - __uint_as_float(((unsigned)h1) << 16));
  }
}

// ---- prepass: V fp32 -> bf16 (row-major [i][p][q]); W -> Wt bf16 [i][p] ----
__global__ void prep_k(const float* __restrict__ V, const float* __restrict__ W,
                       unsigned short* __restrict__ vhi, unsigned short* __restrict__ wt) {
  int idx = blockIdx.x * 256 + threadIdx.x;
  if (idx < kH * kH2 * kH2) {
    vhi[idx] = f2bf(V[idx]);
  } else {
    int widx = idx - kH * kH2 * kH2;
    if (widx < kH * kH2) {
      int i = widx >> 7, p = widx & 127;
      wt[widx] = f2bf(W[p * kH + i]);      // Wt[i][p] = W[p][i]
    }
  }
}

// ---- fused combine level: out[m,i] = tanh(c_m^T V_i c_m + (W^T c_m)_i + b_i)
// 8-WAVE OCTANT SPLIT (this round): block = 512 threads, wave w owns the
// (m-half = w>>2) x (pt-half = (w>>1)&1) x (ks-half = w&1) octant of the
// per-ic bilinear. Each V-fragment read feeds 4 MFMAs (mt 0..3) and each
// wave reads only 8 KB of V per ic (vs 32 KB before) -> LDS read pipe (the
// measured 64% bottleneck) halves; occupancy doubles to 16 waves/CU.
// Partials combine via one ds_add_f32 per lane (quad j owns m-tile j).
// Math identical to R11 (C-hi-only xVx, hi/lo Wx); only summation order moves.
template<bool FIRST>
__global__ __launch_bounds__(512, 4) void combine2_k(
    const float* __restrict__ in, const int* __restrict__ tokens,
    const float* __restrict__ embed, const unsigned short* __restrict__ vhi,
    const unsigned short* __restrict__ wt, const float* __restrict__ bias,
    float* __restrict__ out, int M, int IS)
{
  __shared__ unsigned short Vs[2][kH2 * kH2]; // 2 x 32 KB, XOR-swizzled chunks
  __shared__ float res[128 * 17];             // Wx+bias, then += xVx partials

  const int t = threadIdx.x;
  const int lane = t & 63, w = t >> 6;       // 8 waves
  const int c = lane & 15, q = lane >> 4;
  const int kh = w & 1;                      // ks-half: ks = kh*2 + ksl
  const int ph = (w >> 1) & 1;               // pt-half: pt = ph*4 + ptl
  const int mg = w >> 2;                     // m-group: 64 rows
  const int m0 = (int)blockIdx.x * 128;
  const int i0 = (int)blockIdx.y * IS;
  const int Mrows = (M < 128) ? M : 128;
  const bool has_rows = (mg * 64) < Mrows;
  const bool dw = (kh == 0) && (ph == 0);    // Wx-designated wave (w==0 or 4)

  bf16x8 bh[4][2];      // C hi fragments: [mt][ksl]
  f32x4  Cred[4][4];    // C fp32 for the p-dot: [mt][ptl]

  if (has_rows) {
    #pragma unroll
    for (int mt = 0; mt < 4; ++mt) {
      int m = m0 + mg * 64 + mt * 16 + c;
      const float* crow = nullptr;
      int tokA = 0, tokB = 0;
      if (FIRST) {                           // level 1: gather from embed
        int b = m >> 8, j = m & 255;         // Nout=256
        tokA = tokens[b * kL + 2 * j];
        tokB = tokens[b * kL + 2 * j + 1];
      } else {
        crow = in + (size_t)m * kH2;
      }
      if (dw) {
        // full-K hi/lo Wx for this mt; keep kh=0 fragments (ks 0,1)
        bf16x8 h4[4], l4[4];
        #pragma unroll
        for (int ks = 0; ks < 4; ++ks) {
          int q0 = ks * 32 + q * 8;
          const float* src = FIRST
              ? (embed + (size_t)(q0 < 64 ? tokA : tokB) * kH + (q0 & 63))
              : (crow + q0);
          f32x4 v0 = *(const f32x4*)src;
          f32x4 v1 = *(const f32x4*)(src + 4);
          cvt8(v0, v1, h4[ks], l4[ks]);
        }
        int irow = i0 + c; if (irow > 63) irow = 63;
        f32x4 ah = {0.f,0.f,0.f,0.f}, al = ah;
        #pragma unroll
        for (int ks = 0; ks < 4; ++ks) {
          bf16x8 a = *(const bf16x8*)(wt + (size_t)irow * kH2 + ks * 32 + q * 8);
          ah = __builtin_amdgcn_mfma_f32_16x16x32_bf16(a, h4[ks], ah, 0, 0, 0);
          al = __builtin_amdgcn_mfma_f32_16x16x32_bf16(a, l4[ks], al, 0, 0, 0);
        }
        #pragma unroll
        for (int reg = 0; reg < 4; ++reg) {
          int ii = q * 4 + reg;
          if (ii < IS)
            res[(mg * 64 + mt * 16 + c) * 17 + ii] = ah[reg] + al[reg] + bias[i0 + ii];
        }
        bh[mt][0] = h4[0]; bh[mt][1] = h4[1];
      } else {
        #pragma unroll
        for (int ksl = 0; ksl < 2; ++ksl) {
          int ks = kh * 2 + ksl;
          int q0 = ks * 32 + q * 8;
          const float* src = FIRST
              ? (embed + (size_t)(q0 < 64 ? tokA : tokB) * kH + (q0 & 63))
              : (crow + q0);
          f32x4 v0 = *(const f32x4*)src;
          f32x4 v1 = *(const f32x4*)(src + 4);
          bf16x8 lo_dummy;
          cvt8(v0, v1, bh[mt][ksl], lo_dummy);   // lo chain DCE'd
        }
      }
      #pragma unroll
      for (int ptl = 0; ptl < 4; ++ptl) {      // reduction copy (its pt-half)
        int p0 = (ph * 4 + ptl) * 16 + q * 4;
        const float* src = FIRST
            ? (embed + (size_t)(p0 < 64 ? tokA : tokB) * kH + (p0 & 63))
            : (crow + p0);
        Cred[mt][ptl] = *(const f32x4*)src;
      }
    }
  }

  // V_i staging: XOR-chunk swizzle, global_load_lds width=16 (8 waves, r<4)
  auto stageV = [&](int i, int buf) {
    const unsigned short* vsrc = vhi + (size_t)i * (kH2 * kH2);
    #pragma unroll
    for (int r = 0; r < 4; ++r) {
      int chunk = w * 256 + r * 64 + lane;   // 2048 physical 16B chunks
      int p  = chunk >> 4;
      int pc = chunk & 15;
      int cc = pc ^ (p & 7);                 // logical chunk in V row p
      const unsigned short* g = vsrc + p * kH2 + cc * 8;
      __builtin_amdgcn_global_load_lds(
          (const __attribute__((address_space(1))) unsigned int*)g,
          (__attribute__((address_space(3))) unsigned int*)
              ((char*)&Vs[buf][0] + (size_t)chunk * 16),
          16, 0, 0);
    }
  };

  // one ic's octant partial out of buffer `buf`; one ds_add per lane
  auto computeIC = [&](int ic, int buf) {
    const char* vbase = (const char*)&Vs[buf][0];
    float g0 = 0.f, g1 = 0.f, g2 = 0.f, g3 = 0.f;
    #pragma unroll
    for (int ptl = 0; ptl < 4; ++ptl) {
      int p = (ph * 4 + ptl) * 16 + c;
      f32x4 a0 = {0.f,0.f,0.f,0.f}, a1 = a0, a2 = a0, a3 = a0;
      #pragma unroll
      for (int ksl = 0; ksl < 2; ++ksl) {
        int ks = kh * 2 + ksl;
        int cc = (ks * 4 + q) ^ (p & 7);     // swizzled chunk
        bf16x8 vf = *(const bf16x8*)(vbase + (size_t)p * 256 + cc * 16);
        a0 = __builtin_amdgcn_mfma_f32_16x16x32_bf16(vf, bh[0][ksl], a0, 0, 0, 0);
        a1 = __builtin_amdgcn_mfma_f32_16x16x32_bf16(vf, bh[1][ksl], a1, 0, 0, 0);
        a2 = __builtin_amdgcn_mfma_f32_16x16x32_bf16(vf, bh[2][ksl], a2, 0, 0, 0);
        a3 = __builtin_amdgcn_mfma_f32_16x16x32_bf16(vf, bh[3][ksl], a3, 0, 0, 0);
      }
      f32x4 c0 = Cred[0][ptl], c1 = Cred[1][ptl], c2 = Cred[2][ptl], c3 = Cred[3][ptl];
      g0 = fmaf(c0[0], a0[0], g0); g0 = fmaf(c0[1], a0[1], g0);
      g0 = fmaf(c0[2], a0[2], g0); g0 = fmaf(c0[3], a0[3], g0);
      g1 = fmaf(c1[0], a1[0], g1); g1 = fmaf(c1[1], a1[1], g1);
      g1 = fmaf(c1[2], a1[2], g1); g1 = fmaf(c1[3], a1[3], g1);
      g2 = fmaf(c2[0], a2[0], g2); g2 = fmaf(c2[1], a2[1], g2);
      g2 = fmaf(c2[2], a2[2], g2); g2 = fmaf(c2[3], a2[3], g2);
      g3 = fmaf(c3[0], a3[0], g3); g3 = fmaf(c3[1], a3[1], g3);
      g3 = fmaf(c3[2], a3[2], g3); g3 = fmaf(c3[3], a3[3], g3);
    }
    // sum the q-stripes (p-coverage within this wave's pt-half)
    g0 += __shfl_xor(g0, 16); g0 += __shfl_xor(g0, 32);
    g1 += __shfl_xor(g1, 16); g1 += __shfl_xor(g1, 32);
    g2 += __shfl_xor(g2, 16); g2 += __shfl_xor(g2, 32);
    g3 += __shfl_xor(g3, 16); g3 += __shfl_xor(g3, 32);
    float gq = (q == 0) ? g0 : (q == 1) ? g1 : (q == 2) ? g2 : g3;
    atomicAdd(&res[(mg * 64 + q * 16 + c) * 17 + ic], gq);   // ds_add_f32
  };

  if (IS >= 2) {
    stageV(i0, 0); stageV(i0 + 1, 1);
    __syncthreads();
    for (int icp = 0; icp < IS; icp += 2) {
      if (has_rows) {
        computeIC(icp, 0);
        computeIC(icp + 1, 1);
      }
      __syncthreads();                        // V reads + res atomics done
      if (icp + 2 < IS) {
        stageV(i0 + icp + 2, 0); stageV(i0 + icp + 3, 1);
        __syncthreads();
      }
    }
  } else {
    stageV(i0, 0);
    __syncthreads();
    if (has_rows) computeIC(0, 0);
    __syncthreads();
  }

  // epilogue: tanh + store (coalesced over i within row)
  const int sh = __builtin_ctz(IS);
  for (int idx = t; idx < Mrows * IS; idx += 512) {
    int m = idx >> sh, ii = idx & (IS - 1);
    out[(size_t)(m0 + m) * kH + i0 + ii] = tanhf(res[m * 17 + ii]);
  }
}

// ---- head: logits = root @ Wout + bout; log_softmax ----
__global__ void head_k(const float* __restrict__ root,
                       const float* __restrict__ Wout,
                       const float* __restrict__ bout,
                       float* __restrict__ out) {
  int b = threadIdx.x;
  float l[kOut];
  #pragma unroll
  for (int o = 0; o < kOut; ++o) l[o] = bout[o];
  for (int h = 0; h < kH; ++h) {
    float r = root[b * kH + h];
    #pragma unroll
    for (int o = 0; o < kOut; ++o) l[o] = fmaf(r, Wout[h * kOut + o], l[o]);
  }
  float mx = l[0];
  #pragma unroll
  for (int o = 1; o < kOut; ++o) mx = fmaxf(mx, l[o]);
  float s = 0.f;
  #pragma unroll
  for (int o = 0; o < kOut; ++o) s += expf(l[o] - mx);
  float lse = logf(s);
  #pragma unroll
  for (int o = 0; o < kOut; ++o) out[b * kOut + o] = l[o] - mx - lse;
}

extern "C" void kernel_launch(void* const* d_in, const int* in_sizes, int n_in,
                              void* d_out, int out_size, void* d_ws, size_t ws_size,
                              hipStream_t stream) {
  const int*   tokens = (const int*)  d_in[0];
  const float* embed  = (const float*)d_in[1];
  const float* V      = (const float*)d_in[2];
  const float* W      = (const float*)d_in[3];
  const float* bias   = (const float*)d_in[4];
  const float* Wout   = (const float*)d_in[5];
  const float* bout   = (const float*)d_in[6];
  float* out = (float*)d_out;

  // ws layout: vhi 2MB | wt 16KB | bufA 4MB | bufB 2MB  (~8.3 MB total)
  char* ws = (char*)d_ws;
  unsigned short* vhi = (unsigned short*)ws;
  unsigned short* wt  = (unsigned short*)(ws + 2097152);
  float* bufA = (float*)(ws + 2097152 + 16384);
  float* bufB = (float*)(ws + 2097152 + 16384 + 4194304);

  int nprep = kH * kH2 * kH2 + kH * kH2;
  prep_k<<<dim3((nprep + 255) / 256), 256, 0, stream>>>(V, W, vhi, wt);

  const float* cur = nullptr;
  float* nxt = bufA;
  bool first = true;
  for (int Nout = 256; Nout >= 1; Nout >>= 1) {
    int M = kB * Nout;
    int gx = (M + 127) / 128;
    int IS = gx / 8; if (IS < 1) IS = 1; if (IS > 16) IS = 16;
    dim3 grid(gx, 64 / IS);
    if (first)
      combine2_k<true ><<<grid, 512, 0, stream>>>(nullptr, tokens, embed, vhi, wt, bias, nxt, M, IS);
    else
      combine2_k<false><<<grid, 512, 0, stream>>>(cur, nullptr, nullptr, vhi, wt, bias, nxt, M, IS);
    first = false;
    cur = nxt;
    nxt = (nxt == bufA) ? bufB : bufA;
  }
  head_k<<<1, 64, 0, stream>>>(cur, Wout, bout, out);   // cur == bufA (9 levels)
}

// Round 13
// 267.045 us; speedup vs baseline: 1.6635x; 1.6635x over previous
//
#include <hip/hip_runtime.h>
#include <cmath>

// B=64, L=512, H=64, 2H=128, OUT=5
static constexpr int kB = 64, kL = 512, kH = 64, kH2 = 128, kOut = 5;

typedef short bf16x8 __attribute__((ext_vector_type(8)));
typedef float f32x4  __attribute__((ext_vector_type(4)));

__device__ __forceinline__ unsigned short f2bf(float f) {
  unsigned u = __float_as_uint(f);
  unsigned r = (u + 0x7FFFu + ((u >> 16) & 1u)) >> 16;   // RNE
  return (unsigned short)r;
}

__device__ __forceinline__ void cvt8(const f32x4& v0, const f32x4& v1,
                                     bf16x8& hi, bf16x8& lo) {
  #pragma unroll
  for (int j = 0; j < 4; ++j) {
    unsigned short h0 = f2bf(v0[j]);
    unsigned short h1 = f2bf(v1[j]);
    hi[j]     = (short)h0;
    hi[j + 4] = (short)h1;
    lo[j]     = (short)f2bf(v0[j] - __uint_as_float(((unsigned)h0) << 16));
    lo[j + 4] = (short)f2bf(v1[j] - __uint_as_float(((unsigned)h1) << 16));
  }
}

__device__ __forceinline__ void cvt8_hi(const f32x4& v0, const f32x4& v1,
                                        bf16x8& hi) {
  #pragma unroll
  for (int j = 0; j < 4; ++j) {
    hi[j]     = (short)f2bf(v0[j]);
    hi[j + 4] = (short)f2bf(v1[j]);
  }
}

// ---- prepass: V fp32 -> bf16 (row-major [i][p][q]); W -> Wt bf16 [i][p] ----
__global__ void prep_k(const float* __restrict__ V, const float* __restrict__ W,
                       unsigned short* __restrict__ vhi, unsigned short* __restrict__ wt) {
  int idx = blockIdx.x * 256 + threadIdx.x;
  if (idx < kH * kH2 * kH2) {
    vhi[idx] = f2bf(V[idx]);
  } else {
    int widx = idx - kH * kH2 * kH2;
    if (widx < kH * kH2) {
      int i = widx >> 7, p = widx & 127;
      wt[widx] = f2bf(W[p * kH + i]);      // Wt[i][p] = W[p][i]
    }
  }
}

// ---- fused combine level: out[m,i] = tanh(c_m^T V_i c_m + (W^T c_m)_i + b_i)
// 4-WAVE (m-half x pt-half) SPLIT: wave w = (mg = w>>1, ph = w&1) owns 64
// nodes (4 m-tiles) x 4 of 8 pt. Per wave per ic: 16 V-reads (was 32), each
// feeding 4 MFMAs (was 2) -> LDS read pipe (the measured bottleneck) halves.
// ph-halves combine via one LDS atomicAdd per lane (fp32, stride-17 ->
// conflict-free). NO launch-bounds pressure (R12 lesson: forced VGPR cap =
// catastrophic spill); ~180 VGPR needs only 2 waves/SIMD = the LDS-capped
// residency anyway. Math: C-hi-only xVx (R11), hi/lo Wx; reorder-only.
template<bool FIRST>
__global__ __launch_bounds__(256) void combine2_k(
    const float* __restrict__ in, const int* __restrict__ tokens,
    const float* __restrict__ embed, const unsigned short* __restrict__ vhi,
    const unsigned short* __restrict__ wt, const float* __restrict__ bias,
    float* __restrict__ out, int M, int IS)
{
  __shared__ unsigned short Vs[2][kH2 * kH2]; // 2 x 32 KB, XOR-swizzled chunks
  __shared__ float res[128 * 17];             // Wx+bias, then += xVx partials

  const int t = threadIdx.x;
  const int lane = t & 63, w = t >> 6;       // 4 waves
  const int c = lane & 15, q = lane >> 4;
  const int mg = w >> 1;                     // m-half: nodes mg*64 .. +64
  const int ph = w & 1;                      // pt-half: pt = ph*4 + ptl
  const int m0 = (int)blockIdx.x * 128;
  const int i0 = (int)blockIdx.y * IS;
  const int Mrows = (M < 128) ? M : 128;
  const bool has_rows = (mg * 64) < Mrows;
  const bool dw = (ph == 0);                 // Wx-designated wave (w = 0, 2)

  bf16x8 bh[4][4];      // C hi fragments: [mt][ks]   (64 VGPR)
  f32x4  Cred[4][4];    // C fp32 for the p-dot: [mt][ptl]  (64 VGPR)

  if (has_rows) {
    #pragma unroll
    for (int mt = 0; mt < 4; ++mt) {
      int m = m0 + mg * 64 + mt * 16 + c;
      const float* crow = nullptr;
      int tokA = 0, tokB = 0;
      if (FIRST) {                           // level 1: gather from embed
        int b = m >> 8, j = m & 255;         // Nout=256
        tokA = tokens[b * kL + 2 * j];
        tokB = tokens[b * kL + 2 * j + 1];
      } else {
        crow = in + (size_t)m * kH2;
      }
      if (dw) {
        // full-K hi/lo Wx for this mt; keep hi fragments for the loop
        bf16x8 l4[4];
        #pragma unroll
        for (int ks = 0; ks < 4; ++ks) {
          int q0 = ks * 32 + q * 8;
          const float* src = FIRST
              ? (embed + (size_t)(q0 < 64 ? tokA : tokB) * kH + (q0 & 63))
              : (crow + q0);
          f32x4 v0 = *(const f32x4*)src;
          f32x4 v1 = *(const f32x4*)(src + 4);
          cvt8(v0, v1, bh[mt][ks], l4[ks]);
        }
        int irow = i0 + c; if (irow > 63) irow = 63;
        f32x4 ah = {0.f,0.f,0.f,0.f}, al = ah;
        #pragma unroll
        for (int ks = 0; ks < 4; ++ks) {
          bf16x8 a = *(const bf16x8*)(wt + (size_t)irow * kH2 + ks * 32 + q * 8);
          ah = __builtin_amdgcn_mfma_f32_16x16x32_bf16(a, bh[mt][ks], ah, 0, 0, 0);
          al = __builtin_amdgcn_mfma_f32_16x16x32_bf16(a, l4[ks], al, 0, 0, 0);
        }
        #pragma unroll
        for (int reg = 0; reg < 4; ++reg) {
          int ii = q * 4 + reg;
          if (ii < IS)
            res[(mg * 64 + mt * 16 + c) * 17 + ii] = ah[reg] + al[reg] + bias[i0 + ii];
        }
      } else {
        #pragma unroll
        for (int ks = 0; ks < 4; ++ks) {
          int q0 = ks * 32 + q * 8;
          const float* src = FIRST
              ? (embed + (size_t)(q0 < 64 ? tokA : tokB) * kH + (q0 & 63))
              : (crow + q0);
          f32x4 v0 = *(const f32x4*)src;
          f32x4 v1 = *(const f32x4*)(src + 4);
          cvt8_hi(v0, v1, bh[mt][ks]);
        }
      }
      #pragma unroll
      for (int ptl = 0; ptl < 4; ++ptl) {    // reduction copy (its pt-half)
        int p0 = (ph * 4 + ptl) * 16 + q * 4;
        const float* src = FIRST
            ? (embed + (size_t)(p0 < 64 ? tokA : tokB) * kH + (p0 & 63))
            : (crow + p0);
        Cred[mt][ptl] = *(const f32x4*)src;
      }
    }
  }

  // V_i staging: XOR-chunk swizzle, global_load_lds width=16, wave-uniform dest
  auto stageV = [&](int i, int buf) {
    const unsigned short* vsrc = vhi + (size_t)i * (kH2 * kH2);
    #pragma unroll
    for (int r = 0; r < 8; ++r) {
      int chunk = w * 512 + r * 64 + lane;   // physical 16B chunk in LDS
      int p  = chunk >> 4;
      int pc = chunk & 15;
      int cc = pc ^ (p & 7);                 // logical chunk in V row p
      const unsigned short* g = vsrc + p * kH2 + cc * 8;
      __builtin_amdgcn_global_load_lds(
          (const __attribute__((address_space(1))) unsigned int*)g,
          (__attribute__((address_space(3))) unsigned int*)
              ((char*)&Vs[buf][0] + (size_t)(w * 512 + r * 64) * 16),
          16, 0, 0);
    }
  };

  // one ic's (m-half x pt-half) partial out of buffer `buf`; atomic combine
  auto computeIC = [&](int ic, int buf) {
    const char* vbase = (const char*)&Vs[buf][0];
    float g0 = 0.f, g1 = 0.f, g2 = 0.f, g3 = 0.f;
    #pragma unroll
    for (int ptl = 0; ptl < 4; ++ptl) {
      int p = (ph * 4 + ptl) * 16 + c;       // A-frag: V row p
      f32x4 a0 = {0.f,0.f,0.f,0.f}, a1 = a0, a2 = a0, a3 = a0;
      #pragma unroll
      for (int ks = 0; ks < 4; ++ks) {
        int cc = (ks * 4 + q) ^ (p & 7);     // swizzled chunk
        bf16x8 vf = *(const bf16x8*)(vbase + (size_t)p * 256 + cc * 16);
        a0 = __builtin_amdgcn_mfma_f32_16x16x32_bf16(vf, bh[0][ks], a0, 0, 0, 0);
        a1 = __builtin_amdgcn_mfma_f32_16x16x32_bf16(vf, bh[1][ks], a1, 0, 0, 0);
        a2 = __builtin_amdgcn_mfma_f32_16x16x32_bf16(vf, bh[2][ks], a2, 0, 0, 0);
        a3 = __builtin_amdgcn_mfma_f32_16x16x32_bf16(vf, bh[3][ks], a3, 0, 0, 0);
      }
      f32x4 c0 = Cred[0][ptl], c1 = Cred[1][ptl], c2 = Cred[2][ptl], c3 = Cred[3][ptl];
      g0 = fmaf(c0[0], a0[0], g0); g0 = fmaf(c0[1], a0[1], g0);
      g0 = fmaf(c0[2], a0[2], g0); g0 = fmaf(c0[3], a0[3], g0);
      g1 = fmaf(c1[0], a1[0], g1); g1 = fmaf(c1[1], a1[1], g1);
      g1 = fmaf(c1[2], a1[2], g1); g1 = fmaf(c1[3], a1[3], g1);
      g2 = fmaf(c2[0], a2[0], g2); g2 = fmaf(c2[1], a2[1], g2);
      g2 = fmaf(c2[2], a2[2], g2); g2 = fmaf(c2[3], a2[3], g2);
      g3 = fmaf(c3[0], a3[0], g3); g3 = fmaf(c3[1], a3[1], g3);
      g3 = fmaf(c3[2], a3[2], g3); g3 = fmaf(c3[3], a3[3], g3);
    }
    // sum q-stripes (covers this wave's p-range); then pick mt = q
    g0 += __shfl_xor(g0, 16); g0 += __shfl_xor(g0, 32);
    g1 += __shfl_xor(g1, 16); g1 += __shfl_xor(g1, 32);
    g2 += __shfl_xor(g2, 16); g2 += __shfl_xor(g2, 32);
    g3 += __shfl_xor(g3, 16); g3 += __shfl_xor(g3, 32);
    float gq = (q == 0) ? g0 : (q == 1) ? g1 : (q == 2) ? g2 : g3;
    atomicAdd(&res[(mg * 64 + q * 16 + c) * 17 + ic], gq);   // ds_add_f32
  };

  if (IS >= 2) {
    stageV(i0, 0); stageV(i0 + 1, 1);
    __syncthreads();
    for (int icp = 0; icp < IS; icp += 2) {
      if (has_rows) {
        computeIC(icp, 0);
        computeIC(icp + 1, 1);
      }
      __syncthreads();                        // V reads + res atomics done
      if (icp + 2 < IS) {
        stageV(i0 + icp + 2, 0); stageV(i0 + icp + 3, 1);
        __syncthreads();
      }
    }
  } else {
    stageV(i0, 0);
    __syncthreads();
    if (has_rows) computeIC(0, 0);
    __syncthreads();
  }

  // epilogue: tanh + store (coalesced over i within row)
  const int sh = __builtin_ctz(IS);
  for (int idx = t; idx < Mrows * IS; idx += 256) {
    int m = idx >> sh, ii = idx & (IS - 1);
    out[(size_t)(m0 + m) * kH + i0 + ii] = tanhf(res[m * 17 + ii]);
  }
}

// ---- head: logits = root @ Wout + bout; log_softmax ----
__global__ void head_k(const float* __restrict__ root,
                       const float* __restrict__ Wout,
                       const float* __restrict__ bout,
                       float* __restrict__ out) {
  int b = threadIdx.x;
  float l[kOut];
  #pragma unroll
  for (int o = 0; o < kOut; ++o) l[o] = bout[o];
  for (int h = 0; h < kH; ++h) {
    float r = root[b * kH + h];
    #pragma unroll
    for (int o = 0; o < kOut; ++o) l[o] = fmaf(r, Wout[h * kOut + o], l[o]);
  }
  float mx = l[0];
  #pragma unroll
  for (int o = 1; o < kOut; ++o) mx = fmaxf(mx, l[o]);
  float s = 0.f;
  #pragma unroll
  for (int o = 0; o < kOut; ++o) s += expf(l[o] - mx);
  float lse = logf(s);
  #pragma unroll
  for (int o = 0; o < kOut; ++o) out[b * kOut + o] = l[o] - mx - lse;
}

extern "C" void kernel_launch(void* const* d_in, const int* in_sizes, int n_in,
                              void* d_out, int out_size, void* d_ws, size_t ws_size,
                              hipStream_t stream) {
  const int*   tokens = (const int*)  d_in[0];
  const float* embed  = (const float*)d_in[1];
  const float* V      = (const float*)d_in[2];
  const float* W      = (const float*)d_in[3];
  const float* bias   = (const float*)d_in[4];
  const float* Wout   = (const float*)d_in[5];
  const float* bout   = (const float*)d_in[6];
  float* out = (float*)d_out;

  // ws layout: vhi 2MB | wt 16KB | bufA 4MB | bufB 2MB  (~8.3 MB total)
  char* ws = (char*)d_ws;
  unsigned short* vhi = (unsigned short*)ws;
  unsigned short* wt  = (unsigned short*)(ws + 2097152);
  float* bufA = (float*)(ws + 2097152 + 16384);
  float* bufB = (float*)(ws + 2097152 + 16384 + 4194304);

  int nprep = kH * kH2 * kH2 + kH * kH2;
  prep_k<<<dim3((nprep + 255) / 256), 256, 0, stream>>>(V, W, vhi, wt);

  const float* cur = nullptr;
  float* nxt = bufA;
  bool first = true;
  for (int Nout = 256; Nout >= 1; Nout >>= 1) {
    int M = kB * Nout;
    int gx = (M + 127) / 128;
    int IS = gx / 8; if (IS < 1) IS = 1; if (IS > 16) IS = 16;
    dim3 grid(gx, 64 / IS);
    if (first)
      combine2_k<true ><<<grid, 256, 0, stream>>>(nullptr, tokens, embed, vhi, wt, bias, nxt, M, IS);
    else
      combine2_k<false><<<grid, 256, 0, stream>>>(cur, nullptr, nullptr, vhi, wt, bias, nxt, M, IS);
    first = false;
    cur = nxt;
    nxt = (nxt == bufA) ? bufB : bufA;
  }
  head_k<<<1, 64, 0, stream>>>(cur, Wout, bout, out);   // cur == bufA (9 levels)
}

// Round 14
// 243.201 us; speedup vs baseline: 1.8266x; 1.0980x over previous
//
#include <hip/hip_runtime.h>
#include <cmath>

// B=64, L=512, H=64, 2H=128, OUT=5
static constexpr int kB = 64, kL = 512, kH = 64, kH2 = 128, kOut = 5;

typedef short bf16x8 __attribute__((ext_vector_type(8)));
typedef float f32x4  __attribute__((ext_vector_type(4)));

__device__ __forceinline__ unsigned short f2bf(float f) {
  unsigned u = __float_as_uint(f);
  unsigned r = (u + 0x7FFFu + ((u >> 16) & 1u)) >> 16;   // RNE
  return (unsigned short)r;
}

__device__ __forceinline__ void cvt8(const f32x4& v0, const f32x4& v1,
                                     bf16x8& hi, bf16x8& lo) {
  #pragma unroll
  for (int j = 0; j < 4; ++j) {
    unsigned short h0 = f2bf(v0[j]);
    unsigned short h1 = f2bf(v1[j]);
    hi[j]     = (short)h0;
    hi[j + 4] = (short)h1;
    lo[j]     = (short)f2bf(v0[j] - __uint_as_float(((unsigned)h0) << 16));
    lo[j + 4] = (short)f2bf(v1[j] - __uint_as_float(((unsigned)h1) << 16));
  }
}

// ---- prepass: V fp32 -> bf16 (row-major [i][p][q]); W -> Wt bf16 [i][p] ----
__global__ void prep_k(const float* __restrict__ V, const float* __restrict__ W,
                       unsigned short* __restrict__ vhi, unsigned short* __restrict__ wt) {
  int idx = blockIdx.x * 256 + threadIdx.x;
  if (idx < kH * kH2 * kH2) {
    vhi[idx] = f2bf(V[idx]);
  } else {
    int widx = idx - kH * kH2 * kH2;
    if (widx < kH * kH2) {
      int i = widx >> 7, p = widx & 127;
      wt[widx] = f2bf(W[p * kH + i]);      // Wt[i][p] = W[p][i]
    }
  }
}

// ---- fused combine level: out[m,i] = tanh(c_m^T V_i c_m + (W^T c_m)_i + b_i)
// MFMA orientation: D[p, m] = sum_q V_i[p,q] * C[m,q]  (A = V_i, B = C)
// then R[m,i] = sum_p C[m,p] * D[p,m] via per-lane dot + xor16/xor32 butterfly.
// Structure = R11 (measured best: 2-ic phases, C-hi-only xVx, hi/lo Wx).
// THIS ROUND'S ONLY DELTA: per-ks independent MFMA accumulators — 8 short
// chains per pt-step instead of 2 chains of 4 dependent MFMAs; partials
// summed pairwise in fp32. Removes dependent-MFMA issue stalls; +24 VGPR.
template<bool FIRST>
__global__ __launch_bounds__(256) void combine2_k(
    const float* __restrict__ in, const int* __restrict__ tokens,
    const float* __restrict__ embed, const unsigned short* __restrict__ vhi,
    const unsigned short* __restrict__ wt, const float* __restrict__ bias,
    float* __restrict__ out, int M, int IS)
{
  __shared__ unsigned short Vs[2][kH2 * kH2]; // 2 x 32 KB, XOR-swizzled chunks
  __shared__ float res[128 * 17];             // Wx+bias, then += xVx; pad 17

  const int t = threadIdx.x;
  const int lane = t & 63, w = t >> 6;
  const int c = lane & 15, q = lane >> 4;    // c = B-col (node), q = quad
  const int m0 = (int)blockIdx.x * 128;
  const int i0 = (int)blockIdx.y * IS;
  const int Mrows = (M < 128) ? M : 128;
  const bool has_rows = (w * 32) < Mrows;

  bf16x8 bh[2][4], bl[2][4];   // C hi/lo B-fragments, [mtile][kstep]
  f32x4  Cred[2][8];           // C fp32 for the p-reduction, [mtile][ptile]

  if (has_rows) {
    #pragma unroll
    for (int mt = 0; mt < 2; ++mt) {
      int m = m0 + w * 32 + mt * 16 + c;     // this lane's node row
      const float* crow = nullptr;
      int tokA = 0, tokB = 0;
      if (FIRST) {                           // level 1: gather from embed
        int b = m >> 8, j = m & 255;         // Nout=256
        tokA = tokens[b * kL + 2 * j];
        tokB = tokens[b * kL + 2 * j + 1];
      } else {
        crow = in + (size_t)m * kH2;
      }
      #pragma unroll
      for (int ks = 0; ks < 4; ++ks) {       // B-frag: 8 contiguous q at lane's m
        int q0 = ks * 32 + q * 8;
        const float* src = FIRST
            ? (embed + (size_t)(q0 < 64 ? tokA : tokB) * kH + (q0 & 63))
            : (crow + q0);
        f32x4 v0 = *(const f32x4*)src;
        f32x4 v1 = *(const f32x4*)(src + 4);
        cvt8(v0, v1, bh[mt][ks], bl[mt][ks]);
      }
      #pragma unroll
      for (int pt = 0; pt < 8; ++pt) {       // reduction copy: C[m, pt*16+q*4 ..+4]
        int p0 = pt * 16 + q * 4;
        const float* src = FIRST
            ? (embed + (size_t)(p0 < 64 ? tokA : tokB) * kH + (p0 & 63))
            : (crow + p0);
        Cred[mt][pt] = *(const f32x4*)src;
      }
    }
    // Wx GEMM: D'[i, m] = sum_p Wt[i,p] * C[m,p]; res init = Wx + bias (hi+lo)
    {
      int irow = i0 + c; if (irow > 63) irow = 63;
      f32x4 ah0 = {0.f,0.f,0.f,0.f}, al0 = ah0, ah1 = ah0, al1 = ah0;
      #pragma unroll
      for (int ks = 0; ks < 4; ++ks) {
        bf16x8 a = *(const bf16x8*)(wt + (size_t)irow * kH2 + ks * 32 + q * 8);
        ah0 = __builtin_amdgcn_mfma_f32_16x16x32_bf16(a, bh[0][ks], ah0, 0, 0, 0);
        al0 = __builtin_amdgcn_mfma_f32_16x16x32_bf16(a, bl[0][ks], al0, 0, 0, 0);
        ah1 = __builtin_amdgcn_mfma_f32_16x16x32_bf16(a, bh[1][ks], ah1, 0, 0, 0);
        al1 = __builtin_amdgcn_mfma_f32_16x16x32_bf16(a, bl[1][ks], al1, 0, 0, 0);
      }
      #pragma unroll
      for (int reg = 0; reg < 4; ++reg) {
        int ii = q * 4 + reg;                // i-row within tile
        if (ii < IS) {
          float bv = bias[i0 + ii];
          res[(w * 32 + c) * 17 + ii]      = ah0[reg] + al0[reg] + bv;
          res[(w * 32 + 16 + c) * 17 + ii] = ah1[reg] + al1[reg] + bv;
        }
      }
    }
  }

  // V_i staging: XOR-chunk swizzle, global_load_lds width=16, wave-uniform dest
  auto stageV = [&](int i, int buf) {
    const unsigned short* vsrc = vhi + (size_t)i * (kH2 * kH2);
    #pragma unroll
    for (int r = 0; r < 8; ++r) {
      int chunk = w * 512 + r * 64 + lane;   // physical 16B chunk in LDS
      int p  = chunk >> 4;
      int pc = chunk & 15;
      int cc = pc ^ (p & 7);                 // logical chunk in V row p
      const unsigned short* g = vsrc + p * kH2 + cc * 8;
      __builtin_amdgcn_global_load_lds(
          (const __attribute__((address_space(1))) unsigned int*)g,
          (__attribute__((address_space(3))) unsigned int*)
              ((char*)&Vs[buf][0] + (size_t)(w * 512 + r * 64) * 16),
          16, 0, 0);
    }
  };

  // one ic's bilinear accumulation out of buffer `buf` (C-hi only).
  // Per-ks independent accumulators: 8 chains of single MFMAs per pt-step.
  auto computeIC = [&](int ic, int buf) {
    const char* vbase = (const char*)&Vs[buf][0];
    float g0 = 0.f, g1 = 0.f;
    for (int pt = 0; pt < 8; ++pt) {
      int p = pt * 16 + c;                   // A-frag: V row p
      f32x4 z = {0.f,0.f,0.f,0.f};
      f32x4 s00 = z, s01 = z, s02 = z, s03 = z;  // mt=0, ks=0..3
      f32x4 s10 = z, s11 = z, s12 = z, s13 = z;  // mt=1, ks=0..3
      {
        int cc0 = (0 * 4 + q) ^ (p & 7);
        bf16x8 vf = *(const bf16x8*)(vbase + (size_t)p * 256 + cc0 * 16);
        s00 = __builtin_amdgcn_mfma_f32_16x16x32_bf16(vf, bh[0][0], s00, 0, 0, 0);
        s10 = __builtin_amdgcn_mfma_f32_16x16x32_bf16(vf, bh[1][0], s10, 0, 0, 0);
      }
      {
        int cc1 = (1 * 4 + q) ^ (p & 7);
        bf16x8 vf = *(const bf16x8*)(vbase + (size_t)p * 256 + cc1 * 16);
        s01 = __builtin_amdgcn_mfma_f32_16x16x32_bf16(vf, bh[0][1], s01, 0, 0, 0);
        s11 = __builtin_amdgcn_mfma_f32_16x16x32_bf16(vf, bh[1][1], s11, 0, 0, 0);
      }
      {
        int cc2 = (2 * 4 + q) ^ (p & 7);
        bf16x8 vf = *(const bf16x8*)(vbase + (size_t)p * 256 + cc2 * 16);
        s02 = __builtin_amdgcn_mfma_f32_16x16x32_bf16(vf, bh[0][2], s02, 0, 0, 0);
        s12 = __builtin_amdgcn_mfma_f32_16x16x32_bf16(vf, bh[1][2], s12, 0, 0, 0);
      }
      {
        int cc3 = (3 * 4 + q) ^ (p & 7);
        bf16x8 vf = *(const bf16x8*)(vbase + (size_t)p * 256 + cc3 * 16);
        s03 = __builtin_amdgcn_mfma_f32_16x16x32_bf16(vf, bh[0][3], s03, 0, 0, 0);
        s13 = __builtin_amdgcn_mfma_f32_16x16x32_bf16(vf, bh[1][3], s13, 0, 0, 0);
      }
      f32x4 d0 = (s00 + s01) + (s02 + s03);
      f32x4 d1 = (s10 + s11) + (s12 + s13);
      f32x4 cr0 = Cred[0][pt], cr1 = Cred[1][pt];
      g0 = fmaf(cr0[0], d0[0], g0); g0 = fmaf(cr0[1], d0[1], g0);
      g0 = fmaf(cr0[2], d0[2], g0); g0 = fmaf(cr0[3], d0[3], g0);
      g1 = fmaf(cr1[0], d1[0], g1); g1 = fmaf(cr1[1], d1[1], g1);
      g1 = fmaf(cr1[2], d1[2], g1); g1 = fmaf(cr1[3], d1[3], g1);
    }
    // sum over quads (p covers all 128 after this)
    g0 += __shfl_xor(g0, 16); g0 += __shfl_xor(g0, 32);
    g1 += __shfl_xor(g1, 16); g1 += __shfl_xor(g1, 32);
    if (q == 0)      res[(w * 32 + c) * 17 + ic]      += g0;
    else if (q == 1) res[(w * 32 + 16 + c) * 17 + ic] += g1;
  };

  if (IS >= 2) {
    stageV(i0, 0); stageV(i0 + 1, 1);
    __syncthreads();
    for (int icp = 0; icp < IS; icp += 2) {
      if (has_rows) {
        computeIC(icp, 0);
        computeIC(icp + 1, 1);
      }
      __syncthreads();                        // V reads + res writes done
      if (icp + 2 < IS) {
        stageV(i0 + icp + 2, 0); stageV(i0 + icp + 3, 1);
        __syncthreads();
      }
    }
  } else {
    stageV(i0, 0);
    __syncthreads();
    if (has_rows) computeIC(0, 0);
    __syncthreads();
  }

  // epilogue: tanh + store (coalesced over i within row)
  const int sh = __builtin_ctz(IS);
  for (int idx = t; idx < Mrows * IS; idx += 256) {
    int m = idx >> sh, ii = idx & (IS - 1);
    out[(size_t)(m0 + m) * kH + i0 + ii] = tanhf(res[m * 17 + ii]);
  }
}

// ---- head: logits = root @ Wout + bout; log_softmax ----
__global__ void head_k(const float* __restrict__ root,
                       const float* __restrict__ Wout,
                       const float* __restrict__ bout,
                       float* __restrict__ out) {
  int b = threadIdx.x;
  float l[kOut];
  #pragma unroll
  for (int o = 0; o < kOut; ++o) l[o] = bout[o];
  for (int h = 0; h < kH; ++h) {
    float r = root[b * kH + h];
    #pragma unroll
    for (int o = 0; o < kOut; ++o) l[o] = fmaf(r, Wout[h * kOut + o], l[o]);
  }
  float mx = l[0];
  #pragma unroll
  for (int o = 1; o < kOut; ++o) mx = fmaxf(mx, l[o]);
  float s = 0.f;
  #pragma unroll
  for (int o = 0; o < kOut; ++o) s += expf(l[o] - mx);
  float lse = logf(s);
  #pragma unroll
  for (int o = 0; o < kOut; ++o) out[b * kOut + o] = l[o] - mx - lse;
}

extern "C" void kernel_launch(void* const* d_in, const int* in_sizes, int n_in,
                              void* d_out, int out_size, void* d_ws, size_t ws_size,
                              hipStream_t stream) {
  const int*   tokens = (const int*)  d_in[0];
  const float* embed  = (const float*)d_in[1];
  const float* V      = (const float*)d_in[2];
  const float* W      = (const float*)d_in[3];
  const float* bias   = (const float*)d_in[4];
  const float* Wout   = (const float*)d_in[5];
  const float* bout   = (const float*)d_in[6];
  float* out = (float*)d_out;

  // ws layout: vhi 2MB | wt 16KB | bufA 4MB | bufB 2MB  (~8.3 MB total)
  char* ws = (char*)d_ws;
  unsigned short* vhi = (unsigned short*)ws;
  unsigned short* wt  = (unsigned short*)(ws + 2097152);
  float* bufA = (float*)(ws + 2097152 + 16384);
  float* bufB = (float*)(ws + 2097152 + 16384 + 4194304);

  int nprep = kH * kH2 * kH2 + kH * kH2;
  prep_k<<<dim3((nprep + 255) / 256), 256, 0, stream>>>(V, W, vhi, wt);

  const float* cur = nullptr;
  float* nxt = bufA;
  bool first = true;
  for (int Nout = 256; Nout >= 1; Nout >>= 1) {
    int M = kB * Nout;
    int gx = (M + 127) / 128;
    int IS = gx / 8; if (IS < 1) IS = 1; if (IS > 16) IS = 16;
    dim3 grid(gx, 64 / IS);
    if (first)
      combine2_k<true ><<<grid, 256, 0, stream>>>(nullptr, tokens, embed, vhi, wt, bias, nxt, M, IS);
    else
      combine2_k<false><<<grid, 256, 0, stream>>>(cur, nullptr, nullptr, vhi, wt, bias, nxt, M, IS);
    first = false;
    cur = nxt;
    nxt = (nxt == bufA) ? bufB : bufA;
  }
  head_k<<<1, 64, 0, stream>>>(cur, Wout, bout, out);   // cur == bufA (9 levels)
}

// Round 15
// 205.681 us; speedup vs baseline: 2.1598x; 1.1824x over previous
//
#include <hip/hip_runtime.h>
#include <cmath>

// B=64, L=512, H=64, 2H=128, OUT=5, VOC=32000
static constexpr int kB = 64, kL = 512, kH = 64, kH2 = 128, kOut = 5, kVoc = 32000;

typedef short bf16x8 __attribute__((ext_vector_type(8)));
typedef float f32x4  __attribute__((ext_vector_type(4)));

__device__ __forceinline__ unsigned short f2bf(float f) {
  unsigned u = __float_as_uint(f);
  unsigned r = (u + 0x7FFFu + ((u >> 16) & 1u)) >> 16;   // RNE
  return (unsigned short)r;
}

// ---- prepass: V -> bf16 vhi; W -> Wt bf16 [i][p]; embed -> bf16 ebf ----
__global__ void prep_k(const float* __restrict__ V, const float* __restrict__ W,
                       const float* __restrict__ embed,
                       unsigned short* __restrict__ vhi, unsigned short* __restrict__ wt,
                       unsigned short* __restrict__ ebf) {
  int idx = blockIdx.x * 256 + threadIdx.x;
  if (idx < kH * kH2 * kH2) { vhi[idx] = f2bf(V[idx]); return; }
  idx -= kH * kH2 * kH2;
  if (idx < kH * kH2) {
    int i = idx >> 7, p = idx & 127;
    wt[idx] = f2bf(W[p * kH + i]);         // Wt[i][p] = W[p][i]
    return;
  }
  idx -= kH * kH2;
  if (idx < kVoc * kH) ebf[idx] = f2bf(embed[idx]);
}

// ---- fused combine level: out[m,i] = tanh(c_m^T V_i c_m + (W^T c_m)_i + b_i)
// Structure = R11 (measured best: 2-ic phases, C-hi-only xVx).
// THIS ROUND: bf16 operands PRECOMPUTED — bh loads straight from bf16 buffers
// (embed_bf for L1, prev level's bf16 output otherwise). Zero cvt VALU in the
// prologue (was ~450 ops/lane); Wx drops its lo chain (R11 evidence: lo terms
// are below V/W's own bf16 rounding floor). Cred stays exact fp32.
// Epilogue writes fp32 out (for Cred) + bf16 outbf (for next level's bh).
template<bool FIRST>
__global__ __launch_bounds__(256) void combine2_k(
    const float* __restrict__ in, const unsigned short* __restrict__ inbf,
    const int* __restrict__ tokens, const float* __restrict__ embed,
    const unsigned short* __restrict__ vhi, const unsigned short* __restrict__ wt,
    const float* __restrict__ bias, float* __restrict__ out,
    unsigned short* __restrict__ outbf, int M, int IS)
{
  __shared__ unsigned short Vs[2][kH2 * kH2]; // 2 x 32 KB, XOR-swizzled chunks
  __shared__ float res[128 * 17];             // Wx+bias, then += xVx; pad 17

  const int t = threadIdx.x;
  const int lane = t & 63, w = t >> 6;
  const int c = lane & 15, q = lane >> 4;    // c = B-col (node), q = quad
  const int m0 = (int)blockIdx.x * 128;
  const int i0 = (int)blockIdx.y * IS;
  const int Mrows = (M < 128) ? M : 128;
  const bool has_rows = (w * 32) < Mrows;

  bf16x8 bh[2][4];             // C bf16 B-fragments, [mtile][kstep]
  f32x4  Cred[2][8];           // C fp32 for the p-reduction, [mtile][ptile]

  if (has_rows) {
    #pragma unroll
    for (int mt = 0; mt < 2; ++mt) {
      int m = m0 + w * 32 + mt * 16 + c;     // this lane's node row
      const float* crow = nullptr;
      const unsigned short* brow = nullptr;
      int tokA = 0, tokB = 0;
      if (FIRST) {                           // level 1: gather from embed
        int b = m >> 8, j = m & 255;         // Nout=256
        tokA = tokens[b * kL + 2 * j];
        tokB = tokens[b * kL + 2 * j + 1];
      } else {
        crow = in + (size_t)m * kH2;
        brow = inbf + (size_t)m * kH2;
      }
      #pragma unroll
      for (int ks = 0; ks < 4; ++ks) {       // B-frag: direct bf16 load, no cvt
        int q0 = ks * 32 + q * 8;
        const unsigned short* bsrc = FIRST
            ? (inbf + (size_t)(q0 < 64 ? tokA : tokB) * kH + (q0 & 63))  // embed_bf
            : (brow + q0);
        bh[mt][ks] = *(const bf16x8*)bsrc;
      }
      #pragma unroll
      for (int pt = 0; pt < 8; ++pt) {       // reduction copy: exact fp32
        int p0 = pt * 16 + q * 4;
        const float* src = FIRST
            ? (embed + (size_t)(p0 < 64 ? tokA : tokB) * kH + (p0 & 63))
            : (crow + p0);
        Cred[mt][pt] = *(const f32x4*)src;
      }
    }
    // Wx GEMM (hi-only): res init = Wx + bias
    {
      int irow = i0 + c; if (irow > 63) irow = 63;
      f32x4 ah0 = {0.f,0.f,0.f,0.f}, ah1 = ah0;
      #pragma unroll
      for (int ks = 0; ks < 4; ++ks) {
        bf16x8 a = *(const bf16x8*)(wt + (size_t)irow * kH2 + ks * 32 + q * 8);
        ah0 = __builtin_amdgcn_mfma_f32_16x16x32_bf16(a, bh[0][ks], ah0, 0, 0, 0);
        ah1 = __builtin_amdgcn_mfma_f32_16x16x32_bf16(a, bh[1][ks], ah1, 0, 0, 0);
      }
      #pragma unroll
      for (int reg = 0; reg < 4; ++reg) {
        int ii = q * 4 + reg;                // i-row within tile
        if (ii < IS) {
          float bv = bias[i0 + ii];
          res[(w * 32 + c) * 17 + ii]      = ah0[reg] + bv;
          res[(w * 32 + 16 + c) * 17 + ii] = ah1[reg] + bv;
        }
      }
    }
  }

  // V_i staging: XOR-chunk swizzle, global_load_lds width=16, wave-uniform dest
  auto stageV = [&](int i, int buf) {
    const unsigned short* vsrc = vhi + (size_t)i * (kH2 * kH2);
    #pragma unroll
    for (int r = 0; r < 8; ++r) {
      int chunk = w * 512 + r * 64 + lane;   // physical 16B chunk in LDS
      int p  = chunk >> 4;
      int pc = chunk & 15;
      int cc = pc ^ (p & 7);                 // logical chunk in V row p
      const unsigned short* g = vsrc + p * kH2 + cc * 8;
      __builtin_amdgcn_global_load_lds(
          (const __attribute__((address_space(1))) unsigned int*)g,
          (__attribute__((address_space(3))) unsigned int*)
              ((char*)&Vs[buf][0] + (size_t)(w * 512 + r * 64) * 16),
          16, 0, 0);
    }
  };

  // one ic's bilinear accumulation out of buffer `buf` (R11-identical)
  auto computeIC = [&](int ic, int buf) {
    const char* vbase = (const char*)&Vs[buf][0];
    float g0 = 0.f, g1 = 0.f;
    for (int pt = 0; pt < 8; ++pt) {
      f32x4 a0 = {0.f,0.f,0.f,0.f}, a2 = a0;
      #pragma unroll
      for (int ks = 0; ks < 4; ++ks) {
        int p  = pt * 16 + c;                // A-frag: V row p, 8 bf16 at q-chunk
        int cc = (ks * 4 + q) ^ (p & 7);     // swizzled chunk
        bf16x8 vf = *(const bf16x8*)(vbase + (size_t)p * 256 + cc * 16);
        a0 = __builtin_amdgcn_mfma_f32_16x16x32_bf16(vf, bh[0][ks], a0, 0, 0, 0);
        a2 = __builtin_amdgcn_mfma_f32_16x16x32_bf16(vf, bh[1][ks], a2, 0, 0, 0);
      }
      f32x4 cr0 = Cred[0][pt], cr1 = Cred[1][pt];
      g0 = fmaf(cr0[0], a0[0], g0); g0 = fmaf(cr0[1], a0[1], g0);
      g0 = fmaf(cr0[2], a0[2], g0); g0 = fmaf(cr0[3], a0[3], g0);
      g1 = fmaf(cr1[0], a2[0], g1); g1 = fmaf(cr1[1], a2[1], g1);
      g1 = fmaf(cr1[2], a2[2], g1); g1 = fmaf(cr1[3], a2[3], g1);
    }
    // sum over quads (p covers all 128 after this)
    g0 += __shfl_xor(g0, 16); g0 += __shfl_xor(g0, 32);
    g1 += __shfl_xor(g1, 16); g1 += __shfl_xor(g1, 32);
    if (q == 0)      res[(w * 32 + c) * 17 + ic]      += g0;
    else if (q == 1) res[(w * 32 + 16 + c) * 17 + ic] += g1;
  };

  if (IS >= 2) {
    stageV(i0, 0); stageV(i0 + 1, 1);
    __syncthreads();
    for (int icp = 0; icp < IS; icp += 2) {
      if (has_rows) {
        computeIC(icp, 0);
        computeIC(icp + 1, 1);
      }
      __syncthreads();                        // V reads + res writes done
      if (icp + 2 < IS) {
        stageV(i0 + icp + 2, 0); stageV(i0 + icp + 3, 1);
        __syncthreads();
      }
    }
  } else {
    stageV(i0, 0);
    __syncthreads();
    if (has_rows) computeIC(0, 0);
    __syncthreads();
  }

  // epilogue: tanh + store fp32 (for Cred) and bf16 (for next level's bh)
  const int sh = __builtin_ctz(IS);
  for (int idx = t; idx < Mrows * IS; idx += 256) {
    int m = idx >> sh, ii = idx & (IS - 1);
    float v = tanhf(res[m * 17 + ii]);
    size_t o = (size_t)(m0 + m) * kH + i0 + ii;
    out[o] = v;
    outbf[o] = f2bf(v);
  }
}

// ---- head: logits = root @ Wout + bout; log_softmax ----
__global__ void head_k(const float* __restrict__ root,
                       const float* __restrict__ Wout,
                       const float* __restrict__ bout,
                       float* __restrict__ out) {
  int b = threadIdx.x;
  float l[kOut];
  #pragma unroll
  for (int o = 0; o < kOut; ++o) l[o] = bout[o];
  for (int h = 0; h < kH; ++h) {
    float r = root[b * kH + h];
    #pragma unroll
    for (int o = 0; o < kOut; ++o) l[o] = fmaf(r, Wout[h * kOut + o], l[o]);
  }
  float mx = l[0];
  #pragma unroll
  for (int o = 1; o < kOut; ++o) mx = fmaxf(mx, l[o]);
  float s = 0.f;
  #pragma unroll
  for (int o = 0; o < kOut; ++o) s += expf(l[o] - mx);
  float lse = logf(s);
  #pragma unroll
  for (int o = 0; o < kOut; ++o) out[b * kOut + o] = l[o] - mx - lse;
}

extern "C" void kernel_launch(void* const* d_in, const int* in_sizes, int n_in,
                              void* d_out, int out_size, void* d_ws, size_t ws_size,
                              hipStream_t stream) {
  const int*   tokens = (const int*)  d_in[0];
  const float* embed  = (const float*)d_in[1];
  const float* V      = (const float*)d_in[2];
  const float* W      = (const float*)d_in[3];
  const float* bias   = (const float*)d_in[4];
  const float* Wout   = (const float*)d_in[5];
  const float* bout   = (const float*)d_in[6];
  float* out = (float*)d_out;

  // ws layout (bytes):
  //   vhi   2MB | wt 16KB | ebf 4MB | bufA 4MB | bufB 2MB | bfA 2MB | bfB 1MB
  char* ws = (char*)d_ws;
  unsigned short* vhi = (unsigned short*)ws;
  unsigned short* wt  = (unsigned short*)(ws + 2097152);
  unsigned short* ebf = (unsigned short*)(ws + 2097152 + 16384);
  float* bufA = (float*)(ws + 2097152 + 16384 + 4194304);
  float* bufB = (float*)(ws + 2097152 + 16384 + 4194304 + 4194304);
  unsigned short* bfA = (unsigned short*)(ws + 2097152 + 16384 + 4194304 + 4194304 + 2097152);
  unsigned short* bfB = (unsigned short*)(ws + 2097152 + 16384 + 4194304 + 4194304 + 2097152 + 2097152);

  int nprep = kH * kH2 * kH2 + kH * kH2 + kVoc * kH;
  prep_k<<<dim3((nprep + 255) / 256), 256, 0, stream>>>(V, W, embed, vhi, wt, ebf);

  const float* cur = nullptr;
  const unsigned short* curbf = nullptr;
  float* nxt = bufA;
  unsigned short* nxtbf = bfA;
  bool first = true;
  for (int Nout = 256; Nout >= 1; Nout >>= 1) {
    int M = kB * Nout;
    int gx = (M + 127) / 128;
    int IS = gx / 8; if (IS < 1) IS = 1; if (IS > 16) IS = 16;
    dim3 grid(gx, 64 / IS);
    if (first)
      combine2_k<true ><<<grid, 256, 0, stream>>>(nullptr, ebf, tokens, embed,
                                                  vhi, wt, bias, nxt, nxtbf, M, IS);
    else
      combine2_k<false><<<grid, 256, 0, stream>>>(cur, curbf, nullptr, nullptr,
                                                  vhi, wt, bias, nxt, nxtbf, M, IS);
    first = false;
    cur = nxt; curbf = nxtbf;
    nxt   = (nxt == bufA) ? bufB : bufA;
    nxtbf = (nxtbf == bfA) ? bfB : bfA;
  }
  head_k<<<1, 64, 0, stream>>>(cur, Wout, bout, out);   // cur == bufA (9 levels)
}